// Round 12
// baseline (333.940 us; speedup 1.0000x reference)
//
#include <hip/hip_runtime.h>
#include <math.h>

// Problem shape (fixed by reference setup_inputs):
//   images [32][256][64][64] fp32, words [32][32][768] fp32, mask [32][32] bool,
//   W [256][768] fp32, b [256] fp32
//   out0 weighted_words [32][256][64][64], out1 attn_out [32][32][64][64], fp32.
#define B_   32
#define NC_  256
#define HW_  4096
#define MW_  32
#define E_   768
#define NEG_BIG -3.0e38f

typedef float vf2 __attribute__((ext_vector_type(2)));
typedef float vf4 __attribute__((ext_vector_type(4)));

// Workspace layout (float offsets).
#define PART_OFF   0          // partials: 8 chunks * 32b * 32m * 256c
#define WT_OFF     2359296    // W transposed [e][c]: 196608 floats
#define WORDST_OFF 2555904    // words transposed [b][e][m]: 786432 floats

// ---------------------------------------------------------------------------
// Prep: tiled transposes (W -> WT 768x256; words[b] -> wordsT[b] 768x32).
// ---------------------------------------------------------------------------
__global__ __launch_bounds__(256) void prep_kernel(
    const float* __restrict__ W, const float* __restrict__ words,
    float* __restrict__ WT, float* __restrict__ wordsT) {
  const int tid = threadIdx.x;
  const int tx = tid & 31, ty = tid >> 5;
  if (blockIdx.x < 192) {
    __shared__ float t[32][33];
    const int tc = blockIdx.x / 24, te = blockIdx.x % 24;
    const int c0 = tc * 32, e0 = te * 32;
#pragma unroll
    for (int k = 0; k < 4; ++k) {
      const int r = ty + 8 * k;
      t[r][tx] = W[(c0 + r) * E_ + e0 + tx];
    }
    __syncthreads();
#pragma unroll
    for (int k = 0; k < 4; ++k) {
      const int r = ty + 8 * k;
      WT[(e0 + r) * NC_ + c0 + tx] = t[tx][r];
    }
  } else {
    __shared__ float t[32][33];
    const int idx = blockIdx.x - 192;
    const int b = idx / 24, te = idx % 24;
    const int e0 = te * 32;
    const float* wsrc = words + (size_t)b * MW_ * E_;
    float* wdst = wordsT + (size_t)b * E_ * MW_;
#pragma unroll
    for (int k = 0; k < 4; ++k) {
      const int m = ty + 8 * k;
      t[m][tx] = wsrc[m * E_ + e0 + tx];
    }
    __syncthreads();
#pragma unroll
    for (int k = 0; k < 4; ++k) {
      const int e = ty + 8 * k;
      wdst[(e0 + e) * MW_ + tx] = t[tx][e];
    }
  }
}

// ---------------------------------------------------------------------------
// Stage 1a: words_p partials. part[chunk][b][m][c].
// ---------------------------------------------------------------------------
__global__ __launch_bounds__(256) void stage1_partial(
    const float* __restrict__ wordsT, const float* __restrict__ WT,
    float* __restrict__ part) {
  const int c = threadIdx.x;
  const int b = blockIdx.x >> 3;
  const int chunk = blockIdx.x & 7;
  const int e0 = chunk * 96;
  const float* wt = wordsT + (size_t)b * E_ * MW_;
  float acc[32];
#pragma unroll
  for (int m = 0; m < 32; ++m) acc[m] = 0.f;
#pragma unroll 2
  for (int e = e0; e < e0 + 96; ++e) {
    const float wv = WT[(size_t)e * NC_ + c];
    const float* wr = wt + e * MW_;
#pragma unroll
    for (int m = 0; m < 32; ++m) acc[m] = fmaf(wv, wr[m], acc[m]);
  }
  float* pp = part + ((size_t)chunk * 32 + b) * 32 * 256;
#pragma unroll
  for (int m = 0; m < 32; ++m) pp[m * 256 + c] = acc[m];
}

// ---------------------------------------------------------------------------
// Stage 2 (R12): R10 skeleton at 2 px/thread -- balanced pipes + real TLP.
// Model fitting ALL rounds (ds_read_b128 ~12cyc per-lane / ~4cyc broadcast):
//   per-CU-phase FMA cyc fixed ~33k; LDS cyc = ratio x waves.
//   R4 1px: LDS 65k > FMA -> 47%. R6/R10 2-4px @1 wave/SIMD: balanced but
//   dependency bubbles unfillable -> 46-50%. R8: 2 waves on 2 SIMDs -> 58%.
//   R11 scalar: s_loads return unordered -> lgkmcnt(0) drains kill the
//   pipeline -> 36%/18% duty. Winning cell never tried: 2px (balanced
//   1 b128 : 8 FMA) AND 2 waves/SIMD (bubbles filled by TLP).
// R12: 512 blocks x 256 thr (4 waves = 2 px-groups x 2 c-halves) = 2048
//   waves = 2/SIMD. LDS 66KB -> exactly 2 blocks/CU (LDS-capped; VGPR free:
//   launch_bounds(256,2) cap 256, live ~120-150, no squeeze). Per wave:
//   128 ch x 32 m x 2 px. Exchange = 2 rounds (s0,s1) through the same
//   conflict-free xbuf. Everything else identical to R10 (proven correct).
// ---------------------------------------------------------------------------
__global__ __launch_bounds__(256, 2) void attention_fused(
    const float* __restrict__ images, const float* __restrict__ part,
    const float* __restrict__ bias, const void* __restrict__ mask_raw,
    float* __restrict__ out_w, float* __restrict__ out_a) {
  __shared__ float lwp[NC_ * MW_];   // [c][m], 32 KB
  __shared__ vf4 xbuf[2][8][128];    // exchange: [h][quad][q], 32 KB
  __shared__ int is_word;
  const int tid = threadIdx.x;            // 0..255
  const int lane = tid & 63;
  const int w = tid >> 6;                 // wave 0..3
  const int h = w & 1;                    // c-half of this wave
  const int q = lane + ((w >> 1) << 6);   // px-thread 0..127
  const int b = blockIdx.x & 31;          // batch (batch-minor grid)
  const int po = ((blockIdx.x >> 5) << 7) + q;  // vf2 col in [0,2048)
  // image base for this wave's channel half, pre-offset by po (vf2 units)
  const vf2* imgh = (const vf2*)(images + (size_t)b * NC_ * HW_)
                    + (((size_t)(h << 7)) << 11) + po;

  if (tid == 0) is_word = 1;

  // Image prefetch FIRST -- flies during staging below.
  vf2 cur[8];
#pragma unroll
  for (int j = 0; j < 8; ++j)
    cur[j] = __builtin_nontemporal_load(&imgh[(size_t)j << 11]);

  // Fused staging-reduce: lwp[c][m] = bias[c] + sum_k part[k][b][m][c].
  // Thread owns vf4 chunks v: (c = v>>3, mq = v&7) -> lane-consecutive
  // writes (conflict-free, R8/R10-verified); coalesced part reads.
  {
    vf4* dst = (vf4*)lwp;
#pragma unroll
    for (int k2 = 0; k2 < 8; ++k2) {
      const int v = tid + (k2 << 8);
      const int c = v >> 3;
      const int mq = v & 7;
      const float bc = bias[c];
      float v0 = bc, v1 = bc, v2 = bc, v3 = bc;
#pragma unroll
      for (int pk = 0; pk < 8; ++pk) {
        const float* pp = part + (((size_t)pk * 32 + b) * 32) * 256;
        const int mb = mq << 2;
        v0 += pp[(mb + 0) * 256 + c];
        v1 += pp[(mb + 1) * 256 + c];
        v2 += pp[(mb + 2) * 256 + c];
        v3 += pp[(mb + 3) * 256 + c];
      }
      vf4 t; t.x = v0; t.y = v1; t.z = v2; t.w = v3;
      dst[v] = t;
    }
  }

  // Mask layout probe (first 1024 bytes only: safe for any layout).
  {
    const int* mi = (const int*)mask_raw;
    const int vv = mi[tid];
    if (vv != 0 && vv != 1 && vv != 0x3F800000) is_word = 0;
  }
  __syncthreads();  // lwp ready; is_word final
  unsigned mbits = 0;
  if (is_word) {
    const int* mi = (const int*)mask_raw;
#pragma unroll
    for (int m = 0; m < 32; ++m)
      mbits |= (mi[(b << 5) + m] != 0 ? 1u : 0u) << m;
  } else {
    const unsigned char* mb = (const unsigned char*)mask_raw;
#pragma unroll
    for (int m = 0; m < 32; ++m)
      mbits |= (mb[(b << 5) + m] != 0 ? 1u : 0u) << m;
  }

  // ---- score loop: this wave's 128 channels, 2 px ----
  float s0[32], s1[32];
#pragma unroll
  for (int m = 0; m < 32; ++m) { s0[m] = 0.f; s1[m] = 0.f; }

#pragma unroll 1
  for (int c0 = 0; c0 < 128; c0 += 8) {
    vf2 nxt[8];
    if (c0 + 8 < 128) {
#pragma unroll
      for (int j = 0; j < 8; ++j)
        nxt[j] = __builtin_nontemporal_load(&imgh[(size_t)(c0 + 8 + j) << 11]);
    }
#pragma unroll
    for (int j = 0; j < 8; ++j) {
      const float* wr = lwp + (((h << 7) + c0 + j) << 5);  // broadcast row
      const vf2 v = cur[j];
#pragma unroll
      for (int m = 0; m < 32; ++m) {
        s0[m] = fmaf(v.x, wr[m], s0[m]);
        s1[m] = fmaf(v.y, wr[m], s1[m]);
      }
    }
#pragma unroll
    for (int j = 0; j < 8; ++j) cur[j] = nxt[j];  // dead on last iter
  }

  // ---- all-reduce partial scores between wave pairs (h <-> h^1) ----
  // 2 rounds (one per px), each moving all 8 quads; conflict-free vf4.
  const int ho = h ^ 1;
#define XCHG(SV)                                                        \
  {                                                                     \
    _Pragma("unroll")                                                   \
    for (int vq = 0; vq < 8; ++vq) {                                    \
      vf4 t;                                                            \
      t.x = SV[4*vq]; t.y = SV[4*vq+1]; t.z = SV[4*vq+2]; t.w = SV[4*vq+3]; \
      xbuf[h][vq][q] = t;                                               \
    }                                                                   \
    __syncthreads();                                                    \
    _Pragma("unroll")                                                   \
    for (int vq = 0; vq < 8; ++vq) {                                    \
      const vf4 t = xbuf[ho][vq][q];                                    \
      SV[4*vq] += t.x; SV[4*vq+1] += t.y;                               \
      SV[4*vq+2] += t.z; SV[4*vq+3] += t.w;                             \
    }                                                                   \
  }
  XCHG(s0);
  __syncthreads();
  XCHG(s1);
#undef XCHG

  // ---- softmax over m, 2 px (scale 1/sqrt(256) = 0.0625) ----
  // Both waves of a pair hold identical sums -> redundant (uniform) softmax.
  float mx0 = NEG_BIG, mx1 = NEG_BIG;
#pragma unroll
  for (int m = 0; m < 32; ++m) {
    s0[m] *= 0.0625f; s1[m] *= 0.0625f;
    if (!((mbits >> m) & 1u)) {
      mx0 = fmaxf(mx0, s0[m]); mx1 = fmaxf(mx1, s1[m]);
    }
  }
  float sum0 = 0.f, sum1 = 0.f;
#pragma unroll
  for (int m = 0; m < 32; ++m) {
    const bool msk = (mbits >> m) & 1u;
    const float e0 = msk ? 0.f : __expf(s0[m] - mx0);
    const float e1 = msk ? 0.f : __expf(s1[m] - mx1);
    s0[m] = e0; s1[m] = e1;
    sum0 += e0; sum1 += e1;
  }
  const float inv0 = 1.f / sum0, inv1 = 1.f / sum1;
#pragma unroll
  for (int m = 0; m < 32; ++m) { s0[m] *= inv0; s1[m] *= inv1; }

  if (h == 0) {
    vf2* oa = (vf2*)out_a;
#pragma unroll
    for (int m = 0; m < 32; ++m) {
      vf2 a; a.x = s0[m]; a.y = s1[m];
      __builtin_nontemporal_store(a, &oa[(((size_t)(b << 5) + m) << 11) + po]);
    }
  }

  // ---- PV loop: this wave's 128 channels, 2 px ----
  vf2* ow = (vf2*)out_w;
#pragma unroll 1
  for (int c0 = 0; c0 < 128; c0 += 8) {
#pragma unroll
    for (int j = 0; j < 8; ++j) {
      const int c = (h << 7) + c0 + j;
      const float* wr = lwp + (c << 5);
      float o0 = 0.f, o1 = 0.f;
#pragma unroll
      for (int m = 0; m < 32; ++m) {
        o0 = fmaf(wr[m], s0[m], o0);
        o1 = fmaf(wr[m], s1[m], o1);
      }
      vf2 o; o.x = o0; o.y = o1;
      __builtin_nontemporal_store(o, &ow[(((size_t)(b << 8) + c) << 11) + po]);
    }
  }
}

// ---------------------------------------------------------------------------
extern "C" void kernel_launch(void* const* d_in, const int* in_sizes, int n_in,
                              void* d_out, int out_size, void* d_ws, size_t ws_size,
                              hipStream_t stream) {
  const float* images = (const float*)d_in[0];
  const float* words  = (const float*)d_in[1];
  const void*  mask   = d_in[2];
  const float* W      = (const float*)d_in[3];
  const float* bias   = (const float*)d_in[4];

  float* ws     = (float*)d_ws;
  float* part   = ws + PART_OFF;
  float* WT     = ws + WT_OFF;
  float* wordsT = ws + WORDST_OFF;

  float* out_w = (float*)d_out;
  float* out_a = out_w + (size_t)B_ * NC_ * HW_;

  prep_kernel<<<960, 256, 0, stream>>>(W, words, WT, wordsT);
  stage1_partial<<<256, 256, 0, stream>>>(wordsT, WT, part);
  attention_fused<<<512, 256, 0, stream>>>(images, part, bias, mask, out_w, out_a);
}

// Round 13
// 307.857 us; speedup vs baseline: 1.0847x; 1.0847x over previous
//
#include <hip/hip_runtime.h>
#include <math.h>

// Problem shape (fixed by reference setup_inputs):
//   images [32][256][64][64] fp32, words [32][32][768] fp32, mask [32][32] bool,
//   W [256][768] fp32, b [256] fp32
//   out0 weighted_words [32][256][64][64], out1 attn_out [32][32][64][64], fp32 concat.
#define B_   32
#define NC_  256
#define HW_  4096
#define MW_  32
#define E_   768
#define NEG_BIG -3.0e38f

// Native Clang vector types: __builtin_nontemporal_* accepts these
// (HIP's float2/float4 are classes and are rejected -- R5 compile failure).
typedef float vf2 __attribute__((ext_vector_type(2)));
typedef float vf4 __attribute__((ext_vector_type(4)));

// Workspace layout (float offsets). Total ~13.4 MB.
#define PART_OFF   0          // partial GEMM: 8 chunks * 32b * 32m * 256c = 2097152 floats
#define WP_OFF     2097152    // words_p [b][c][m]: 262144 floats
#define WT_OFF     2359296    // W transposed [e][c]: 196608 floats
#define WORDST_OFF 2555904    // words transposed [b][e][m]: 786432 floats
#define MASK_OFF   3342336    // normalized mask: 1024 ints

// ---------------------------------------------------------------------------
// Prep: tiled transposes (W 256x768 -> WT 768x256; words[b] 32x768 ->
// wordsT[b] 768x32) + mask normalization.
// Blocks 0..191: W transpose. 192..959: words transpose. 960: mask.
// ---------------------------------------------------------------------------
__global__ __launch_bounds__(256) void prep_kernel(
    const float* __restrict__ W, const float* __restrict__ words,
    const void* __restrict__ mask_raw,
    float* __restrict__ WT, float* __restrict__ wordsT,
    int* __restrict__ maskn) {
  const int tid = threadIdx.x;
  const int tx = tid & 31, ty = tid >> 5;
  if (blockIdx.x < 192) {
    // W: 32x32 tile transpose; tiles: 8 (c) x 24 (e)
    __shared__ float t[32][33];
    const int tc = blockIdx.x / 24, te = blockIdx.x % 24;
    const int c0 = tc * 32, e0 = te * 32;
#pragma unroll
    for (int k = 0; k < 4; ++k) {
      const int r = ty + 8 * k;
      t[r][tx] = W[(c0 + r) * E_ + e0 + tx];  // coalesced over tx
    }
    __syncthreads();
#pragma unroll
    for (int k = 0; k < 4; ++k) {
      const int r = ty + 8 * k;
      WT[(e0 + r) * NC_ + c0 + tx] = t[tx][r];  // coalesced over tx
    }
  } else if (blockIdx.x < 960) {
    // words[b]: 32(m) x 768(e) -> wordsT[b]: 768(e) x 32(m). tiles: 32 b x 24 e
    __shared__ float t[32][33];
    const int idx = blockIdx.x - 192;
    const int b = idx / 24, te = idx % 24;
    const int e0 = te * 32;
    const float* wsrc = words + (size_t)b * MW_ * E_;
    float* wdst = wordsT + (size_t)b * E_ * MW_;
#pragma unroll
    for (int k = 0; k < 4; ++k) {
      const int m = ty + 8 * k;
      t[m][tx] = wsrc[m * E_ + e0 + tx];        // coalesced over tx (e)
    }
    __syncthreads();
#pragma unroll
    for (int k = 0; k < 4; ++k) {
      const int e = ty + 8 * k;
      wdst[(e0 + e) * MW_ + tx] = t[tx][e];     // coalesced over tx (m)
    }
  } else {
    // Mask layout detection + normalize to int[1024].
    __shared__ int is_word;  // 1 if 4-byte-per-element layout (int32 or fp32)
    if (tid == 0) is_word = 1;
    __syncthreads();
    const int* mi = (const int*)mask_raw;
    const int v = mi[tid];  // reads only first 1024 bytes: safe for any layout
    if (v != 0 && v != 1 && v != 0x3F800000) is_word = 0;
    __syncthreads();
    if (is_word) {
#pragma unroll
      for (int j = 0; j < 4; ++j) { const int i = j * 256 + tid; maskn[i] = (mi[i] != 0); }
    } else {
      const unsigned char* mb = (const unsigned char*)mask_raw;
#pragma unroll
      for (int j = 0; j < 4; ++j) { const int i = j * 256 + tid; maskn[i] = (mb[i] != 0); }
    }
  }
}

// ---------------------------------------------------------------------------
// Stage 1a: words_p partials. Block = (batch, e-chunk of 96). lane = c.
// ---------------------------------------------------------------------------
__global__ __launch_bounds__(256) void stage1_partial(
    const float* __restrict__ wordsT, const float* __restrict__ WT,
    float* __restrict__ part) {
  const int c = threadIdx.x;
  const int b = blockIdx.x >> 3;
  const int chunk = blockIdx.x & 7;
  const int e0 = chunk * 96;
  const float* wt = wordsT + (size_t)b * E_ * MW_;
  float acc[32];
#pragma unroll
  for (int m = 0; m < 32; ++m) acc[m] = 0.f;
#pragma unroll 2
  for (int e = e0; e < e0 + 96; ++e) {
    const float wv = WT[(size_t)e * NC_ + c];   // coalesced over lanes
    const float* wr = wt + e * MW_;             // uniform, contiguous
#pragma unroll
    for (int m = 0; m < 32; ++m) acc[m] = fmaf(wv, wr[m], acc[m]);
  }
  float* pp = part + ((size_t)chunk * 32 + b) * 32 * 256;
#pragma unroll
  for (int m = 0; m < 32; ++m) pp[m * 256 + c] = acc[m];  // coalesced
}

// ---------------------------------------------------------------------------
// Stage 1b: reduce 8 partials + bias -> wp[b][c][m] (m contiguous for stage 2).
// ---------------------------------------------------------------------------
__global__ __launch_bounds__(256) void stage1_reduce(
    const float* __restrict__ part, const float* __restrict__ bias,
    float* __restrict__ wp) {
  const int idx = blockIdx.x * 256 + threadIdx.x;  // (b, m, c), c innermost
  const int c = idx & 255;
  const int m = (idx >> 8) & 31;
  const int b = idx >> 13;
  float s = bias[c];
#pragma unroll
  for (int k = 0; k < 8; ++k)
    s += part[(((size_t)k * 32 + b) * 32 + m) * 256 + c];  // coalesced
  wp[((size_t)b * 256 + c) * 32 + m] = s;
}

// ---------------------------------------------------------------------------
// Stage 2 (FINAL = R6, measured best: attn 93.8us, total 308.7us):
// LDS-wp + 2 px/thread (native ext_vector float2).
// Session findings locked into this shape:
//   - wp MUST come from LDS, not s_load (R0: scalar stream stalls, 21% duty;
//     R11: deep s_load streams can't be pipelined -- unordered returns force
//     lgkmcnt(0) drains, 18% duty).
//   - 2 px/thread balances LDS-read:FMA at 1 b128 : 8 FMA-insts (R4's 1px
//     is LDS-pipe-bound at 47%).
//   - Compiler-scheduled inner loops ONLY (R7: manual reg ping-pong +21%
//     VALU-cycles, 144us).
//   - No launch-bounds minimum beyond 1 (R1-R3: allocator squeeze ->
//     spills at VGPR caps 64/48/102).
//   - c-split/m-split/4px variants (R8/R10/R12) are all neutral-to-worse:
//     VALU busy-time is invariant ~47us across every structure; barrier-
//     lockstep waves cannot fill each other's bubbles. This 94us is the
//     structural ceiling of the fp32-vector formulation; the remaining gap
//     to the ~43us memory floor is only reachable via split-bf16 MFMA.
// ---------------------------------------------------------------------------
__global__ __launch_bounds__(128, 1) void attention_fused(
    const float* __restrict__ images, const float* __restrict__ wp,
    const int* __restrict__ maskn, float* __restrict__ out_w,
    float* __restrict__ out_a) {
  __shared__ float lwp[NC_ * MW_];  // 32 KB: wp[b] resident per block
  const int tid = threadIdx.x;           // 0..127
  const int b = blockIdx.x & 31;         // batch-minor: CU/XCD-mates share b
  const int po = ((blockIdx.x >> 5) << 7) + tid;  // vf2 idx in [0,2048)
  const vf2* imgb = (const vf2*)(images + (size_t)b * NC_ * HW_);

  // Issue image prefetch FIRST -- flies during the LDS staging below.
  vf2 cur[16];
#pragma unroll
  for (int j = 0; j < 16; ++j)
    cur[j] = __builtin_nontemporal_load(&imgb[((size_t)j << 11) + po]);

  // Stage wp[b] -> LDS (2048 vf4 over 128 threads, coalesced).
  {
    const vf4* src = (const vf4*)(wp + (size_t)b * NC_ * MW_);
    vf4* dst = (vf4*)lwp;
#pragma unroll
    for (int k = 0; k < 16; ++k) dst[tid + (k << 7)] = src[tid + (k << 7)];
  }
  __syncthreads();

  // scores for the pixel pair: s{0,1}[m] = sum_c img[c,p{0,1}] * wp[c,m]
  float s0[32], s1[32];
#pragma unroll
  for (int m = 0; m < 32; ++m) { s0[m] = 0.f; s1[m] = 0.f; }

#pragma unroll 1
  for (int c0 = 0; c0 < 256; c0 += 16) {
    vf2 nxt[16];
    if (c0 + 16 < 256) {
#pragma unroll
      for (int j = 0; j < 16; ++j)
        nxt[j] = __builtin_nontemporal_load(&imgb[((size_t)(c0 + 16 + j) << 11) + po]);
    }
#pragma unroll
    for (int j = 0; j < 16; ++j) {
      const float* wrow = lwp + ((c0 + j) << 5);  // broadcast LDS row
      const vf2 v = cur[j];
#pragma unroll
      for (int m = 0; m < 32; ++m) {
        s0[m] = fmaf(v.x, wrow[m], s0[m]);
        s1[m] = fmaf(v.y, wrow[m], s1[m]);
      }
    }
#pragma unroll
    for (int j = 0; j < 16; ++j) cur[j] = nxt[j];  // dead on last iter
  }

  // mask bits (wave-uniform)
  unsigned mbits = 0;
#pragma unroll
  for (int m = 0; m < 32; ++m)
    mbits |= (maskn[(b << 5) + m] != 0 ? 1u : 0u) << m;

  // softmax over m for both pixels (scale 1/sqrt(256)); masked -> exactly 0
  float mx0 = NEG_BIG, mx1 = NEG_BIG;
#pragma unroll
  for (int m = 0; m < 32; ++m) {
    s0[m] *= 0.0625f;
    s1[m] *= 0.0625f;
    if (!((mbits >> m) & 1u)) {
      mx0 = fmaxf(mx0, s0[m]);
      mx1 = fmaxf(mx1, s1[m]);
    }
  }
  float sum0 = 0.f, sum1 = 0.f;
#pragma unroll
  for (int m = 0; m < 32; ++m) {
    const bool msk = (mbits >> m) & 1u;
    const float e0 = msk ? 0.f : __expf(s0[m] - mx0);
    const float e1 = msk ? 0.f : __expf(s1[m] - mx1);
    s0[m] = e0; s1[m] = e1;
    sum0 += e0; sum1 += e1;
  }
  const float inv0 = 1.f / sum0, inv1 = 1.f / sum1;
  vf2* oa = (vf2*)out_a;
#pragma unroll
  for (int m = 0; m < 32; ++m) {
    s0[m] *= inv0;
    s1[m] *= inv1;
    vf2 a; a.x = s0[m]; a.y = s1[m];
    __builtin_nontemporal_store(a, &oa[((size_t)((b << 5) + m) << 11) + po]);
  }

  // weighted words: out[c,p] = sum_m wp[c,m] * a[m]  (wp rows shared by pair)
  vf2* ow = (vf2*)out_w;
#pragma unroll 1
  for (int c0 = 0; c0 < 256; c0 += 8) {
#pragma unroll
    for (int jc = 0; jc < 8; ++jc) {
      const int c = c0 + jc;
      const float* wrow = lwp + (c << 5);
      float o0 = 0.f, o1 = 0.f;
#pragma unroll
      for (int m = 0; m < 32; ++m) {
        o0 = fmaf(wrow[m], s0[m], o0);
        o1 = fmaf(wrow[m], s1[m], o1);
      }
      vf2 o; o.x = o0; o.y = o1;
      __builtin_nontemporal_store(o, &ow[((size_t)((b << 8) + c) << 11) + po]);
    }
  }
}

// ---------------------------------------------------------------------------
extern "C" void kernel_launch(void* const* d_in, const int* in_sizes, int n_in,
                              void* d_out, int out_size, void* d_ws, size_t ws_size,
                              hipStream_t stream) {
  const float* images = (const float*)d_in[0];
  const float* words  = (const float*)d_in[1];
  const void*  mask   = d_in[2];
  const float* W      = (const float*)d_in[3];
  const float* bias   = (const float*)d_in[4];

  float* ws     = (float*)d_ws;
  float* part   = ws + PART_OFF;
  float* wp     = ws + WP_OFF;
  float* WT     = ws + WT_OFF;
  float* wordsT = ws + WORDST_OFF;
  int*   maskn  = (int*)(ws + MASK_OFF);

  float* out_w = (float*)d_out;
  float* out_a = out_w + (size_t)B_ * NC_ * HW_;

  prep_kernel<<<961, 256, 0, stream>>>(W, words, mask, WT, wordsT, maskn);
  stage1_partial<<<256, 256, 0, stream>>>(wordsT, WT, part);
  stage1_reduce<<<1024, 256, 0, stream>>>(part, bias, wp);
  attention_fused<<<512, 128, 0, stream>>>(images, wp, maskn, out_w, out_a);
}